// Round 2
// baseline (928.420 us; speedup 1.0000x reference)
//
#include <hip/hip_runtime.h>
#include <math.h>

// ---------------------------------------------------------------------------
// TaggingQuantizer: cosine-distance VQ assignment + loss + pos/neg reorder.
//   z: (65536, 256) f32,  W: (1024, 256) f32
//   out: emb (1024*256) | label (1024) | loss (1)   all f32, flat-concat.
//
// Strategy: bf16 MFMA screening (candidates within DELTA of running best)
//           + exact fp32 rescore of candidates (winner == fp32 argmax).
// ---------------------------------------------------------------------------

typedef unsigned short u16;
typedef unsigned int   u32;
typedef __attribute__((ext_vector_type(8))) short short8;  // 8 bf16 (4 VGPRs)
typedef __attribute__((ext_vector_type(4))) float f32x4;

#define N_E   1024
#define E_DIM 256
#define N_TOK 65536
#define BETA  0.25f
#define CAP   16
#define DELTA 0.125f

// ws layout (bytes):
#define WS_INVNORM 0          // float[1024]
#define WS_MASK    4096       // int[1024]
#define WS_RANK    8192       // int[1024]
#define WS_LACC    12288      // double
#define WS_WSW     16384      // u16[1024*256] swizzled bf16 Wn (512 KB)
#define WS_CNT     540672     // u32[65536]
#define WS_CAND    802816     // u16[65536*CAP] (2 MB)

// round-to-nearest-even f32 -> bf16 bits
static __device__ __forceinline__ u16 f2bf(float f) {
    u32 u = __float_as_uint(f);
    u32 r = (u + 0x7FFFu + ((u >> 16) & 1u)) >> 16;
    return (u16)r;
}
// monotone float <-> uint key (for atomicMax on ordered floats)
static __device__ __forceinline__ u32 keyenc(float f) {
    u32 u = __float_as_uint(f);
    return u ^ (u32)(((int)u >> 31) | 0x80000000);
}
static __device__ __forceinline__ float keydec(u32 k) {
    u32 u = (k & 0x80000000u) ? (k ^ 0x80000000u) : ~k;
    return __uint_as_float(u);
}

// --------------------------------------------------------------------------
// K1 prep: per-code inverse norms + build swizzled bf16 normalized W in
// MFMA B-fragment order: Wsw[nb(8)][kc(8)][nt(8)][lane(64)][j(8)],
// where for code n, k:  nb=n>>7, nt=(n>>4)&7, col=n&15,
//                       kc=k>>5, q=(k>>3)&3, j=k&7, lane=q*16+col.
// Also zero mask + loss accumulator (ws is re-poisoned each call).
// --------------------------------------------------------------------------
__global__ void k_prep(const float* __restrict__ W, u16* __restrict__ Wsw,
                       float* __restrict__ inv_norm, int* __restrict__ mask,
                       double* __restrict__ lacc) {
    const int n = blockIdx.x;      // 1024
    const int l = threadIdx.x;     // 64
    const float4 v = reinterpret_cast<const float4*>(W + (size_t)n * E_DIM)[l];
    float s = v.x * v.x + v.y * v.y + v.z * v.z + v.w * v.w;
#pragma unroll
    for (int sh = 1; sh < 64; sh <<= 1) s += __shfl_xor(s, sh, 64);
    const float inv = 1.0f / sqrtf(s);
    if (l == 0) {
        inv_norm[n] = inv;
        mask[n] = 0;
        if (n == 0) *lacc = 0.0;
    }
    // lane l holds k = 4l..4l+3  -> octet o = l>>1, j0 = (l&1)*4
    const int o = l >> 1;
    const int kc = o >> 2, q = o & 3;
    const size_t base =
        (((((size_t)(n >> 7) * 8 + kc) * 8 + ((n >> 4) & 7)) * 64 +
          (q * 16 + (n & 15))) * 8) + (l & 1) * 4;
    u16* dst = Wsw + base;
    dst[0] = f2bf(v.x * inv);
    dst[1] = f2bf(v.y * inv);
    dst[2] = f2bf(v.z * inv);
    dst[3] = f2bf(v.w * inv);
}

// --------------------------------------------------------------------------
// K2 score: bf16 MFMA over 128 tokens x all 1024 codes; collect per-token
// candidate codes whose bf16 score >= running_best - DELTA.
// LDS: A (z bf16, fragment order, 64KB) + B chunk (8KB) + epi (~5KB).
// --------------------------------------------------------------------------
__global__ __launch_bounds__(256, 2)
void k_score(const float* __restrict__ z, const u16* __restrict__ Wsw,
             u16* __restrict__ cand_g, u32* __restrict__ cnt_g) {
    __shared__ u16 A_sw[32768];        // [kc(8)][mt(8)][lane(64)][j(8)]
    __shared__ u16 B_sw[4096];         // [nt(8)][lane(64)][j(8)]
    __shared__ u32 bestk[128];
    __shared__ u32 cnt[128];
    __shared__ u16 cand[128 * CAP];

    const int t    = threadIdx.x;
    const int lane = t & 63;
    const int w    = t >> 6;
    const int mq   = w >> 1;           // token half (0/1)
    const int nq   = w & 1;            // code half (0/1)
    const size_t tok_base = (size_t)blockIdx.x * 128;

    // ---- phase 0: convert z tile (128x256) to bf16 A-fragments in LDS ----
#pragma unroll 4
    for (int i = 0; i < 16; i++) {
        const int c = t + 256 * i;     // chunk id: 128 rows x 32 octets
        const int m = c >> 5, o = c & 31;
        const float* zp = z + (tok_base + m) * E_DIM + o * 8;
        const float4 v0 = reinterpret_cast<const float4*>(zp)[0];
        const float4 v1 = reinterpret_cast<const float4*>(zp)[1];
        uint4 d;
        d.x = (u32)f2bf(v0.x) | ((u32)f2bf(v0.y) << 16);
        d.y = (u32)f2bf(v0.z) | ((u32)f2bf(v0.w) << 16);
        d.z = (u32)f2bf(v1.x) | ((u32)f2bf(v1.y) << 16);
        d.w = (u32)f2bf(v1.z) | ((u32)f2bf(v1.w) << 16);
        const int kc = o >> 2, q = o & 3, col = m & 15, mt = m >> 4;
        *reinterpret_cast<uint4*>(A_sw + ((size_t)((kc * 8 + mt) * 64 + q * 16 + col)) * 8) = d;
    }
    if (t < 128) { bestk[t] = 0u; cnt[t] = 0u; }

    const int q   = lane >> 4;
    const int col = lane & 15;
    float thr[16];

#pragma unroll 1
    for (int nb = 0; nb < 8; nb++) {
        f32x4 acc[4][4];
#pragma unroll
        for (int mi = 0; mi < 4; mi++)
#pragma unroll
            for (int ni = 0; ni < 4; ni++) {
                f32x4 zf = {0.f, 0.f, 0.f, 0.f};
                acc[mi][ni] = zf;
            }

#pragma unroll 1
        for (int kc = 0; kc < 8; kc++) {
            __syncthreads();  // previous chunk's B readers done
            // stage B chunk (8 KB, contiguous, coalesced)
            const uint4* src = reinterpret_cast<const uint4*>(Wsw + (size_t)(nb * 8 + kc) * 4096);
            uint4* dst = reinterpret_cast<uint4*>(B_sw);
            dst[t]       = src[t];
            dst[t + 256] = src[t + 256];
            __syncthreads();

            short8 af[4], bf[4];
#pragma unroll
            for (int mi = 0; mi < 4; mi++)
                af[mi] = *reinterpret_cast<const short8*>(
                    A_sw + ((size_t)((kc * 8 + mq * 4 + mi) * 64 + lane)) * 8);
#pragma unroll
            for (int ni = 0; ni < 4; ni++)
                bf[ni] = *reinterpret_cast<const short8*>(
                    B_sw + ((size_t)((nq * 4 + ni) * 64 + lane)) * 8);
#pragma unroll
            for (int mi = 0; mi < 4; mi++)
#pragma unroll
                for (int ni = 0; ni < 4; ni++)
                    acc[mi][ni] = __builtin_amdgcn_mfma_f32_16x16x32_bf16(
                        af[mi], bf[ni], acc[mi][ni], 0, 0, 0);
        }

        // ---- epilogue: thresholds + candidate admission ----
        if (nb == 0) {
            // seed: per-token max over this wave's 64-code half
#pragma unroll
            for (int mi = 0; mi < 4; mi++)
#pragma unroll
                for (int r = 0; r < 4; r++) {
                    float m0 = fmaxf(fmaxf(acc[mi][0][r], acc[mi][1][r]),
                                     fmaxf(acc[mi][2][r], acc[mi][3][r]));
#pragma unroll
                    for (int sh = 1; sh < 16; sh <<= 1)
                        m0 = fmaxf(m0, __shfl_xor(m0, sh, 64));
                    thr[mi * 4 + r] = m0 - DELTA;
                }
        } else {
#pragma unroll
            for (int mi = 0; mi < 4; mi++)
#pragma unroll
                for (int r = 0; r < 4; r++) {
                    const int tok = mq * 64 + mi * 16 + q * 4 + r;
                    thr[mi * 4 + r] = keydec(bestk[tok]) - DELTA;
                }
        }
#pragma unroll
        for (int mi = 0; mi < 4; mi++)
#pragma unroll
            for (int ni = 0; ni < 4; ni++)
#pragma unroll
                for (int r = 0; r < 4; r++) {
                    const float v = acc[mi][ni][r];
                    if (v >= thr[mi * 4 + r]) {
                        const int tok  = mq * 64 + mi * 16 + q * 4 + r;
                        const int code = nb * 128 + nq * 64 + ni * 16 + col;
                        const u32 slot = atomicAdd(&cnt[tok], 1u);
                        if (slot < CAP) cand[tok * CAP + slot] = (u16)code;
                        atomicMax(&bestk[tok], keyenc(v));
                    }
                }
    }

    __syncthreads();
    // write out candidate lists
    if (t < 128) cnt_g[tok_base + t] = cnt[t];
    reinterpret_cast<uint4*>(cand_g + tok_base * CAP)[t] =
        reinterpret_cast<const uint4*>(cand)[t];
}

// --------------------------------------------------------------------------
// K3 pick: fp32 rescore of candidates -> exact winner (lowest idx on ties),
// fused loss partial sums + pos-mask scatter. One wave per token.
// --------------------------------------------------------------------------
__global__ __launch_bounds__(256)
void k_pick(const float* __restrict__ z, const float* __restrict__ W,
            const float* __restrict__ inv_norm, const u16* __restrict__ cand_g,
            const u32* __restrict__ cnt_g, int* __restrict__ mask,
            double* __restrict__ lacc) {
    const int t = threadIdx.x, lane = t & 63, w = t >> 6;
    float lsum = 0.f;
#pragma unroll 1
    for (int it = 0; it < 16; it++) {
        const int tok = (blockIdx.x * 4 + w) * 16 + it;
        const float4 zv = reinterpret_cast<const float4*>(z + (size_t)tok * E_DIM)[lane];
        const u32 c0 = cnt_g[tok];
        float bv = -3.4e38f;
        int   bi = 0x7FFFFFFF;
        if (c0 >= 1 && c0 <= CAP) {
            for (u32 i = 0; i < c0; i++) {
                const int c = cand_g[(size_t)tok * CAP + i];
                const float4 wv = reinterpret_cast<const float4*>(W + (size_t)c * E_DIM)[lane];
                float p = zv.x * wv.x + zv.y * wv.y + zv.z * wv.z + zv.w * wv.w;
#pragma unroll
                for (int sh = 1; sh < 64; sh <<= 1) p += __shfl_xor(p, sh, 64);
                const float s = p * inv_norm[c];
                if (s > bv || (s == bv && c < bi)) { bv = s; bi = c; }
            }
        } else {
            // overflow / defensive: exact full scan
            for (int c = 0; c < N_E; c++) {
                const float4 wv = reinterpret_cast<const float4*>(W + (size_t)c * E_DIM)[lane];
                float p = zv.x * wv.x + zv.y * wv.y + zv.z * wv.z + zv.w * wv.w;
#pragma unroll
                for (int sh = 1; sh < 64; sh <<= 1) p += __shfl_xor(p, sh, 64);
                const float s = p * inv_norm[c];
                if (s > bv || (s == bv && c < bi)) { bv = s; bi = c; }
            }
        }
        const float4 wv = reinterpret_cast<const float4*>(W + (size_t)bi * E_DIM)[lane];
        const float dx = zv.x - wv.x, dy = zv.y - wv.y;
        const float dz2 = zv.z - wv.z, dw = zv.w - wv.w;
        lsum += dx * dx + dy * dy + dz2 * dz2 + dw * dw;
        if (lane == 0) mask[bi] = 1;   // benign race
    }
#pragma unroll
    for (int sh = 1; sh < 64; sh <<= 1) lsum += __shfl_xor(lsum, sh, 64);
    if (lane == 0) atomicAdd(lacc, (double)lsum);
}

// --------------------------------------------------------------------------
// K4 scan: 1-block prefix scan over mask -> rank (pos-first stable order),
// plus loss finalize.
// --------------------------------------------------------------------------
__global__ void k_scan(const int* __restrict__ mask, int* __restrict__ rank,
                       const double* __restrict__ lacc, float* __restrict__ loss_out) {
    __shared__ int buf[N_E];
    const int t = threadIdx.x;             // 1024
    const int m = mask[t];
    buf[t] = m;
    __syncthreads();
    for (int off = 1; off < N_E; off <<= 1) {
        const int v = (t >= off) ? buf[t - off] : 0;
        __syncthreads();
        buf[t] += v;
        __syncthreads();
    }
    const int incl  = buf[t];
    const int total = buf[N_E - 1];
    rank[t] = m ? (incl - m) : (total + t - (incl - m));
    if (t == 0) {
        const double mse = (*lacc) / (double)((size_t)N_TOK * E_DIM);
        *loss_out = (float)((1.0 + (double)BETA) * mse);
    }
}

// --------------------------------------------------------------------------
// K5 emit: emb[rank[e]] = W[e]; label[rank[e]] = mask[e].
// --------------------------------------------------------------------------
__global__ void k_emit(const float* __restrict__ W, const int* __restrict__ rank,
                       const int* __restrict__ mask, float* __restrict__ out) {
    const int e = blockIdx.x;              // 1024
    const int t = threadIdx.x;             // 256
    const int r = rank[e];
    out[(size_t)r * E_DIM + t] = W[(size_t)e * E_DIM + t];
    if (t == 0) out[(size_t)N_E * E_DIM + r] = mask[e] ? 1.0f : 0.0f;
}

// --------------------------------------------------------------------------
extern "C" void kernel_launch(void* const* d_in, const int* in_sizes, int n_in,
                              void* d_out, int out_size, void* d_ws, size_t ws_size,
                              hipStream_t stream) {
    const float* z = (const float*)d_in[0];
    const float* W = (const float*)d_in[1];
    float* out = (float*)d_out;
    char* ws = (char*)d_ws;

    float*  inv_norm = (float*)(ws + WS_INVNORM);
    int*    mask     = (int*)(ws + WS_MASK);
    int*    rank     = (int*)(ws + WS_RANK);
    double* lacc     = (double*)(ws + WS_LACC);
    u16*    Wsw      = (u16*)(ws + WS_WSW);
    u32*    cnt      = (u32*)(ws + WS_CNT);
    u16*    cand     = (u16*)(ws + WS_CAND);

    float* loss_out = out + (size_t)N_E * E_DIM + N_E;  // 263168

    k_prep <<<N_E, 64, 0, stream>>>(W, Wsw, inv_norm, mask, lacc);
    k_score<<<N_TOK / 128, 256, 0, stream>>>(z, Wsw, cand, cnt);
    k_pick <<<N_TOK / 64, 256, 0, stream>>>(z, W, inv_norm, cand, cnt, mask, lacc);
    k_scan <<<1, N_E, 0, stream>>>(mask, rank, lacc, loss_out);
    k_emit <<<N_E, 256, 0, stream>>>(W, rank, mask, out);
}

// Round 3
// 184.570 us; speedup vs baseline: 5.0302x; 5.0302x over previous
//
#include <hip/hip_runtime.h>
#include <math.h>

// ---------------------------------------------------------------------------
// TaggingQuantizer: cosine-distance VQ assignment + loss + pos/neg reorder.
//   z: (65536, 256) f32,  W: (1024, 256) f32
//   out: emb (1024*256) | label (1024) | loss (1)   all f32, flat-concat.
//
// bf16 MFMA screening with chunk-inclusive thresholds + final-best compaction
// (most tokens exit with a unique survivor == exact fp32 argmax), then a
// parallel fp32 rescore/loss kernel (16 lanes per token).
// ---------------------------------------------------------------------------

typedef unsigned short u16;
typedef unsigned int   u32;
typedef __attribute__((ext_vector_type(8))) short short8;  // 8 bf16 (4 VGPRs)
typedef __attribute__((ext_vector_type(4))) float f32x4;

#define N_E   1024
#define E_DIM 256
#define N_TOK 65536
#define BETA  0.25f
#define CAP   16
#define D_ADM 0.08f   // admission: >= 10 sigma of pairwise bf16-dot error
#define D_FIL 0.09f   // final filter: D_ADM + fix16 truncation + margin

// ws layout (bytes):
#define WS_INVNORM 0          // float[1024]
#define WS_MASK    4096       // int[1024]
#define WS_RANK    8192       // int[1024]
#define WS_LACC    12288      // double[256]  (ends 14336)
#define WS_WSW     16384      // u16[1024*256] swizzled bf16 Wn (512 KB)
#define WS_CNT     540672     // u32[65536]
#define WS_CAND    802816     // u16[65536*16] (2 MB)

// round-to-nearest-even f32 -> bf16 bits
static __device__ __forceinline__ u16 f2bf(float f) {
    u32 u = __float_as_uint(f);
    u32 r = (u + 0x7FFFu + ((u >> 16) & 1u)) >> 16;
    return (u16)r;
}
// monotone float <-> uint key (for atomicMax on ordered floats)
static __device__ __forceinline__ u32 keyenc(float f) {
    u32 u = __float_as_uint(f);
    return u ^ (u32)(((int)u >> 31) | 0x80000000);
}
static __device__ __forceinline__ float keydec(u32 k) {
    u32 u = (k & 0x80000000u) ? (k ^ 0x80000000u) : ~k;
    return __uint_as_float(u);
}

// --------------------------------------------------------------------------
// K1 prep: per-code inverse norms + swizzled bf16 normalized W in MFMA
// B-fragment order: Wsw[nb(8)][kc(8)][nt(8)][lane(64)][j(8)].
// Also zero mask + loss accumulators (ws is re-poisoned each call).
// --------------------------------------------------------------------------
__global__ void k_prep(const float* __restrict__ W, u16* __restrict__ Wsw,
                       float* __restrict__ inv_norm, int* __restrict__ mask,
                       double* __restrict__ lacc) {
    const int n = blockIdx.x;      // 1024
    const int l = threadIdx.x;     // 64
    const float4 v = reinterpret_cast<const float4*>(W + (size_t)n * E_DIM)[l];
    float s = v.x * v.x + v.y * v.y + v.z * v.z + v.w * v.w;
#pragma unroll
    for (int sh = 1; sh < 64; sh <<= 1) s += __shfl_xor(s, sh, 64);
    const float inv = 1.0f / sqrtf(s);
    if (l == 0) {
        inv_norm[n] = inv;
        mask[n] = 0;
        if (n < 256) lacc[n] = 0.0;
    }
    // lane l holds k = 4l..4l+3  -> octet o = l>>1
    const int o = l >> 1;
    const int kc = o >> 2, q = o & 3;
    const size_t base =
        (((((size_t)(n >> 7) * 8 + kc) * 8 + ((n >> 4) & 7)) * 64 +
          (q * 16 + (n & 15))) * 8) + (l & 1) * 4;
    u16* dst = Wsw + base;
    dst[0] = f2bf(v.x * inv);
    dst[1] = f2bf(v.y * inv);
    dst[2] = f2bf(v.z * inv);
    dst[3] = f2bf(v.w * inv);
}

// --------------------------------------------------------------------------
// K2 score: bf16 MFMA, 128 tokens x 1024 codes per block. B fragments come
// straight from L2-hot swizzled global (no B LDS, 1 barrier per chunk).
// Chunk-inclusive thresholds -> admit -> compact against final best.
// LDS: A 64KB + bestk/cnt 1KB + slots 8KB = 74.75 KB -> 2 blocks/CU.
// --------------------------------------------------------------------------
__global__ __launch_bounds__(256, 2)
void k_score(const float* __restrict__ z, const u16* __restrict__ Wsw,
             u16* __restrict__ cand_g, u32* __restrict__ cnt_g) {
    __shared__ u16 A_sw[32768];        // [kc(8)][mt(8)][lane(64)][j(8)]
    __shared__ u32 bestk[128];
    __shared__ u32 cnt[128];
    __shared__ u32 slots[128 * CAP];   // (fix16 score << 16) | code

    const int t    = threadIdx.x;
    const int lane = t & 63;
    const int w    = t >> 6;
    const int mq   = w >> 1;           // token half
    const int nq   = w & 1;            // code half
    const size_t tok_base = (size_t)blockIdx.x * 128;

    if (t < 128) { bestk[t] = 0u; cnt[t] = 0u; }

    // ---- phase 0: convert z tile (128x256) to bf16 A-fragments in LDS ----
#pragma unroll 4
    for (int i = 0; i < 16; i++) {
        const int c = t + 256 * i;     // 128 rows x 32 octets
        const int m = c >> 5, o = c & 31;
        const float* zp = z + (tok_base + m) * E_DIM + o * 8;
        const float4 v0 = reinterpret_cast<const float4*>(zp)[0];
        const float4 v1 = reinterpret_cast<const float4*>(zp)[1];
        uint4 d;
        d.x = (u32)f2bf(v0.x) | ((u32)f2bf(v0.y) << 16);
        d.y = (u32)f2bf(v0.z) | ((u32)f2bf(v0.w) << 16);
        d.z = (u32)f2bf(v1.x) | ((u32)f2bf(v1.y) << 16);
        d.w = (u32)f2bf(v1.z) | ((u32)f2bf(v1.w) << 16);
        const int kc = o >> 2, q = o & 3, col = m & 15, mt = m >> 4;
        *reinterpret_cast<uint4*>(A_sw + ((size_t)((kc * 8 + mt) * 64 + q * 16 + col)) * 8) = d;
    }
    __syncthreads();

    const int q   = lane >> 4;
    const int col = lane & 15;
    const u16* wb = Wsw + (size_t)(nq * 4) * 512 + (size_t)lane * 8;

#pragma unroll 1
    for (int nb = 0; nb < 8; nb++) {
        f32x4 acc[4][4];
#pragma unroll
        for (int mi = 0; mi < 4; mi++)
#pragma unroll
            for (int ni = 0; ni < 4; ni++) {
                f32x4 zf = {0.f, 0.f, 0.f, 0.f};
                acc[mi][ni] = zf;
            }

#pragma unroll 2
        for (int kc = 0; kc < 8; kc++) {
            short8 bf[4], af[4];
#pragma unroll
            for (int ni = 0; ni < 4; ni++)
                bf[ni] = *reinterpret_cast<const short8*>(
                    wb + (size_t)(nb * 64 + kc * 8 + ni) * 512);
#pragma unroll
            for (int mi = 0; mi < 4; mi++)
                af[mi] = *reinterpret_cast<const short8*>(
                    A_sw + ((size_t)((kc * 8 + mq * 4 + mi) * 64 + lane)) * 8);
#pragma unroll
            for (int mi = 0; mi < 4; mi++)
#pragma unroll
                for (int ni = 0; ni < 4; ni++)
                    acc[mi][ni] = __builtin_amdgcn_mfma_f32_16x16x32_bf16(
                        af[mi], bf[ni], acc[mi][ni], 0, 0, 0);
        }

        // ---- chunk-inclusive max -> bestk ----
#pragma unroll
        for (int mi = 0; mi < 4; mi++)
#pragma unroll
            for (int r = 0; r < 4; r++) {
                float m0 = fmaxf(fmaxf(acc[mi][0][r], acc[mi][1][r]),
                                 fmaxf(acc[mi][2][r], acc[mi][3][r]));
#pragma unroll
                for (int sh = 1; sh < 16; sh <<= 1)
                    m0 = fmaxf(m0, __shfl_xor(m0, sh, 64));
                if (col == 0)
                    atomicMax(&bestk[mq * 64 + mi * 16 + q * 4 + r], keyenc(m0));
            }
        __syncthreads();   // both nq-waves' chunk maxes visible

        float thr[16];
#pragma unroll
        for (int mi = 0; mi < 4; mi++)
#pragma unroll
            for (int r = 0; r < 4; r++)
                thr[mi * 4 + r] = keydec(bestk[mq * 64 + mi * 16 + q * 4 + r]) - D_ADM;

        // admission (later-chunk races only tighten thresholds -> still safe)
#pragma unroll
        for (int mi = 0; mi < 4; mi++)
#pragma unroll
            for (int ni = 0; ni < 4; ni++)
#pragma unroll
                for (int r = 0; r < 4; r++) {
                    const float v = acc[mi][ni][r];
                    if (v >= thr[mi * 4 + r]) {
                        const int tok  = mq * 64 + mi * 16 + q * 4 + r;
                        const int code = nb * 128 + nq * 64 + ni * 16 + col;
                        const u32 slot = atomicAdd(&cnt[tok], 1u);
                        if (slot < CAP) {
                            const float vc = fminf(fmaxf((v + 16.0f) * 1024.0f, 0.0f), 65535.0f);
                            slots[tok * CAP + slot] = ((u32)vc << 16) | (u32)code;
                        }
                    }
                }
    }

    __syncthreads();
    // ---- compaction vs final best ----
    if (t < 128) {
        const size_t tokg = tok_base + t;
        const u32 c = cnt[t];
        if (c > CAP) {
            cnt_g[tokg] = 0xFFFFFFFFu;           // overflow sentinel -> full scan
        } else {
            const float thrf = keydec(bestk[t]) - D_FIL;
            u32 m = 0;
            for (u32 i = 0; i < c; i++) {
                const u32 s = slots[t * CAP + i];
                const float approx = (float)(s >> 16) * (1.0f / 1024.0f) - 16.0f;
                if (approx >= thrf) cand_g[tokg * 16 + (m++)] = (u16)(s & 0xFFFFu);
            }
            cnt_g[tokg] = m;                      // >= 1 guaranteed
        }
    }
}

// --------------------------------------------------------------------------
// K3 pick: 16 lanes per token. sc==1 -> winner known (no rescore). Else fp32
// rescore survivors (lowest idx on fp32 ties). Fused loss + mask scatter.
// --------------------------------------------------------------------------
__global__ __launch_bounds__(256)
void k_pick(const float* __restrict__ z, const float* __restrict__ W,
            const float* __restrict__ inv_norm, const u16* __restrict__ cand_g,
            const u32* __restrict__ cnt_g, int* __restrict__ mask,
            double* __restrict__ lacc) {
    const int t   = threadIdx.x;
    const int gl  = t & 15;
    const int grp = t >> 4;                       // 0..15
    const size_t tok = (size_t)blockIdx.x * 16 + grp;

    float4 zv[4];
#pragma unroll
    for (int j = 0; j < 4; j++)
        zv[j] = reinterpret_cast<const float4*>(z + tok * E_DIM)[j * 16 + gl];

    const u32 sc = cnt_g[tok];
    int bi;
    if (sc == 1u) {
        bi = cand_g[tok * 16];
    } else {
        float bv = -3.4e38f;
        bi = 0x7FFFFFFF;
        const bool full = (sc == 0xFFFFFFFFu);
        const int n_it = full ? N_E : (int)sc;
#pragma unroll 1
        for (int i = 0; i < n_it; i++) {
            const int c = full ? i : (int)cand_g[tok * 16 + i];
            float p = 0.f;
#pragma unroll
            for (int j = 0; j < 4; j++) {
                const float4 wv = reinterpret_cast<const float4*>(W + (size_t)c * E_DIM)[j * 16 + gl];
                p += zv[j].x * wv.x + zv[j].y * wv.y + zv[j].z * wv.z + zv[j].w * wv.w;
            }
#pragma unroll
            for (int sh = 1; sh < 16; sh <<= 1) p += __shfl_xor(p, sh, 64);
            const float s = p * inv_norm[c];
            if (s > bv || (s == bv && c < bi)) { bv = s; bi = c; }
        }
    }

    float lsum = 0.f;
#pragma unroll
    for (int j = 0; j < 4; j++) {
        const float4 wv = reinterpret_cast<const float4*>(W + (size_t)bi * E_DIM)[j * 16 + gl];
        const float dx = zv[j].x - wv.x, dy = zv[j].y - wv.y;
        const float dz2 = zv[j].z - wv.z, dw = zv[j].w - wv.w;
        lsum += dx * dx + dy * dy + dz2 * dz2 + dw * dw;
    }
    if (gl == 0) mask[bi] = 1;                    // benign race

    __shared__ float red[256];
    red[t] = lsum;
    __syncthreads();
#pragma unroll
    for (int s2 = 128; s2 > 0; s2 >>= 1) {
        if (t < s2) red[t] += red[t + s2];
        __syncthreads();
    }
    if (t == 0) atomicAdd(&lacc[blockIdx.x & 255], (double)red[0]);
}

// --------------------------------------------------------------------------
// K4 scan: prefix scan over mask -> rank (pos-first stable order) + loss.
// --------------------------------------------------------------------------
__global__ void k_scan(const int* __restrict__ mask, int* __restrict__ rank,
                       const double* __restrict__ lacc, float* __restrict__ loss_out) {
    __shared__ int buf[N_E];
    __shared__ double dred[256];
    const int t = threadIdx.x;             // 1024
    const int m = mask[t];
    buf[t] = m;
    if (t < 256) dred[t] = lacc[t];
    __syncthreads();
    for (int off = 1; off < N_E; off <<= 1) {
        const int v = (t >= off) ? buf[t - off] : 0;
        __syncthreads();
        buf[t] += v;
        __syncthreads();
    }
    for (int s2 = 128; s2 >= 1; s2 >>= 1) {
        if (t < s2) dred[t] += dred[t + s2];
        __syncthreads();
    }
    const int incl  = buf[t];
    const int total = buf[N_E - 1];
    rank[t] = m ? (incl - m) : (total + t - (incl - m));
    if (t == 0) {
        const double mse = dred[0] / (double)((size_t)N_TOK * E_DIM);
        *loss_out = (float)((1.0 + (double)BETA) * mse);
    }
}

// --------------------------------------------------------------------------
// K5 emit: emb[rank[e]] = W[e]; label[rank[e]] = mask[e].
// --------------------------------------------------------------------------
__global__ void k_emit(const float* __restrict__ W, const int* __restrict__ rank,
                       const int* __restrict__ mask, float* __restrict__ out) {
    const int e = blockIdx.x;              // 1024
    const int t = threadIdx.x;             // 256
    const int r = rank[e];
    out[(size_t)r * E_DIM + t] = W[(size_t)e * E_DIM + t];
    if (t == 0) out[(size_t)N_E * E_DIM + r] = mask[e] ? 1.0f : 0.0f;
}

// --------------------------------------------------------------------------
extern "C" void kernel_launch(void* const* d_in, const int* in_sizes, int n_in,
                              void* d_out, int out_size, void* d_ws, size_t ws_size,
                              hipStream_t stream) {
    const float* z = (const float*)d_in[0];
    const float* W = (const float*)d_in[1];
    float* out = (float*)d_out;
    char* ws = (char*)d_ws;

    float*  inv_norm = (float*)(ws + WS_INVNORM);
    int*    mask     = (int*)(ws + WS_MASK);
    int*    rank     = (int*)(ws + WS_RANK);
    double* lacc     = (double*)(ws + WS_LACC);
    u16*    Wsw      = (u16*)(ws + WS_WSW);
    u32*    cnt      = (u32*)(ws + WS_CNT);
    u16*    cand     = (u16*)(ws + WS_CAND);

    float* loss_out = out + (size_t)N_E * E_DIM + N_E;  // 263168

    k_prep <<<N_E, 64, 0, stream>>>(W, Wsw, inv_norm, mask, lacc);
    k_score<<<N_TOK / 128, 256, 0, stream>>>(z, Wsw, cand, cnt);
    k_pick <<<N_TOK / 16, 256, 0, stream>>>(z, W, inv_norm, cand, cnt, mask, lacc);
    k_scan <<<1, N_E, 0, stream>>>(mask, rank, lacc, loss_out);
    k_emit <<<N_E, 256, 0, stream>>>(W, rank, mask, out);
}

// Round 4
// 161.847 us; speedup vs baseline: 5.7364x; 1.1404x over previous
//
#include <hip/hip_runtime.h>
#include <math.h>

// ---------------------------------------------------------------------------
// TaggingQuantizer: cosine-distance VQ assignment + loss + pos/neg reorder.
//   z: (65536, 256) f32,  W: (1024, 256) f32
//   out: emb (1024*256) | label (1024) | loss (1)   all f32, flat-concat.
//
// bf16 MFMA screening with chunk-inclusive thresholds + final-best compaction
// (most tokens exit with a unique survivor == exact fp32 argmax), then a
// parallel fp32 rescore/loss kernel, then fused rank+emit.
// ---------------------------------------------------------------------------

typedef unsigned short u16;
typedef unsigned int   u32;
typedef __attribute__((ext_vector_type(8))) short short8;  // 8 bf16 (4 VGPRs)
typedef __attribute__((ext_vector_type(4))) float f32x4;

#define N_E   1024
#define E_DIM 256
#define N_TOK 65536
#define BETA  0.25f
#define CAP   16
#define D_ADM 0.08f   // admission: >= 10 sigma of pairwise bf16-dot error
#define D_FIL 0.09f   // final filter: D_ADM + fix16 truncation + margin

// ws layout (bytes):
#define WS_INVNORM 0          // float[1024]
#define WS_MASK    4096       // int[1024]
#define WS_LACC    12288      // double[256]  (ends 14336)
#define WS_WSW     16384      // u16[1024*256] swizzled bf16 Wn (512 KB)
#define WS_CNT     540672     // u32[65536]
#define WS_CAND    802816     // u16[65536*16] (2 MB)

// round-to-nearest-even f32 -> bf16 bits
static __device__ __forceinline__ u16 f2bf(float f) {
    u32 u = __float_as_uint(f);
    u32 r = (u + 0x7FFFu + ((u >> 16) & 1u)) >> 16;
    return (u16)r;
}
// monotone float <-> uint key (for atomicMax on ordered floats)
static __device__ __forceinline__ u32 keyenc(float f) {
    u32 u = __float_as_uint(f);
    return u ^ (u32)(((int)u >> 31) | 0x80000000);
}
static __device__ __forceinline__ float keydec(u32 k) {
    u32 u = (k & 0x80000000u) ? (k ^ 0x80000000u) : ~k;
    return __uint_as_float(u);
}

// --------------------------------------------------------------------------
// K1 prep: per-code inverse norms + swizzled bf16 normalized W in MFMA
// B-fragment order: Wsw[nb(8)][kc(8)][nt(8)][lane(64)][j(8)].
// Also zero mask + loss accumulators (ws is re-poisoned each call).
// --------------------------------------------------------------------------
__global__ void k_prep(const float* __restrict__ W, u16* __restrict__ Wsw,
                       float* __restrict__ inv_norm, int* __restrict__ mask,
                       double* __restrict__ lacc) {
    const int n = blockIdx.x;      // 1024
    const int l = threadIdx.x;     // 64
    const float4 v = reinterpret_cast<const float4*>(W + (size_t)n * E_DIM)[l];
    float s = v.x * v.x + v.y * v.y + v.z * v.z + v.w * v.w;
#pragma unroll
    for (int sh = 1; sh < 64; sh <<= 1) s += __shfl_xor(s, sh, 64);
    const float inv = 1.0f / sqrtf(s);
    if (l == 0) {
        inv_norm[n] = inv;
        mask[n] = 0;
        if (n < 256) lacc[n] = 0.0;
    }
    // lane l holds k = 4l..4l+3  -> octet o = l>>1
    const int o = l >> 1;
    const int kc = o >> 2, q = o & 3;
    const size_t base =
        (((((size_t)(n >> 7) * 8 + kc) * 8 + ((n >> 4) & 7)) * 64 +
          (q * 16 + (n & 15))) * 8) + (l & 1) * 4;
    u16* dst = Wsw + base;
    dst[0] = f2bf(v.x * inv);
    dst[1] = f2bf(v.y * inv);
    dst[2] = f2bf(v.z * inv);
    dst[3] = f2bf(v.w * inv);
}

// --------------------------------------------------------------------------
// K2 score: bf16 MFMA, 128 tokens x 1024 codes per block, 512 threads
// (8 waves = 4 token-quarters x 2 code-halves; acc 2x4 tiles per wave).
// B fragments straight from L2-hot swizzled global (no B LDS).
// LDS: A 64KB + bestk/cnt 1KB + slots 8KB = 74.75 KB -> 2 blocks/CU
// = 16 waves/CU = 4 waves/SIMD.
// --------------------------------------------------------------------------
__global__ __launch_bounds__(512, 4)
void k_score(const float* __restrict__ z, const u16* __restrict__ Wsw,
             u16* __restrict__ cand_g, u32* __restrict__ cnt_g) {
    __shared__ u16 A_sw[32768];        // [kc(8)][mt(8)][lane(64)][j(8)]
    __shared__ u32 bestk[128];
    __shared__ u32 cnt[128];
    __shared__ u32 slots[128 * CAP];   // (fix16 score << 16) | code

    const int t    = threadIdx.x;      // 512
    const int lane = t & 63;
    const int w    = t >> 6;           // 8 waves
    const int mq2  = w >> 1;           // token quarter (32 tokens)
    const int nq   = w & 1;            // code half
    const size_t tok_base = (size_t)blockIdx.x * 128;

    if (t < 128) { bestk[t] = 0u; cnt[t] = 0u; }

    // ---- phase 0: convert z tile (128x256) to bf16 A-fragments in LDS ----
#pragma unroll
    for (int i = 0; i < 8; i++) {
        const int c = t + 512 * i;     // 128 rows x 32 octets
        const int m = c >> 5, o = c & 31;
        const float* zp = z + (tok_base + m) * E_DIM + o * 8;
        const float4 v0 = reinterpret_cast<const float4*>(zp)[0];
        const float4 v1 = reinterpret_cast<const float4*>(zp)[1];
        uint4 d;
        d.x = (u32)f2bf(v0.x) | ((u32)f2bf(v0.y) << 16);
        d.y = (u32)f2bf(v0.z) | ((u32)f2bf(v0.w) << 16);
        d.z = (u32)f2bf(v1.x) | ((u32)f2bf(v1.y) << 16);
        d.w = (u32)f2bf(v1.z) | ((u32)f2bf(v1.w) << 16);
        const int kc = o >> 2, q = o & 3, col = m & 15, mt = m >> 4;
        *reinterpret_cast<uint4*>(A_sw + ((size_t)((kc * 8 + mt) * 64 + q * 16 + col)) * 8) = d;
    }
    __syncthreads();

    const int q   = lane >> 4;
    const int col = lane & 15;
    const u16* wb = Wsw + (size_t)(nq * 4) * 512 + (size_t)lane * 8;

#pragma unroll 1
    for (int nb = 0; nb < 8; nb++) {
        f32x4 acc[2][4];
#pragma unroll
        for (int mi = 0; mi < 2; mi++)
#pragma unroll
            for (int ni = 0; ni < 4; ni++) {
                f32x4 zf = {0.f, 0.f, 0.f, 0.f};
                acc[mi][ni] = zf;
            }

#pragma unroll 2
        for (int kc = 0; kc < 8; kc++) {
            short8 bf[4], af[2];
#pragma unroll
            for (int ni = 0; ni < 4; ni++)
                bf[ni] = *reinterpret_cast<const short8*>(
                    wb + (size_t)(nb * 64 + kc * 8 + ni) * 512);
#pragma unroll
            for (int mi = 0; mi < 2; mi++)
                af[mi] = *reinterpret_cast<const short8*>(
                    A_sw + ((size_t)((kc * 8 + mq2 * 2 + mi) * 64 + lane)) * 8);
#pragma unroll
            for (int mi = 0; mi < 2; mi++)
#pragma unroll
                for (int ni = 0; ni < 4; ni++)
                    acc[mi][ni] = __builtin_amdgcn_mfma_f32_16x16x32_bf16(
                        af[mi], bf[ni], acc[mi][ni], 0, 0, 0);
        }

        // ---- chunk-inclusive max -> bestk ----
#pragma unroll
        for (int mi = 0; mi < 2; mi++)
#pragma unroll
            for (int r = 0; r < 4; r++) {
                float m0 = fmaxf(fmaxf(acc[mi][0][r], acc[mi][1][r]),
                                 fmaxf(acc[mi][2][r], acc[mi][3][r]));
#pragma unroll
                for (int sh = 1; sh < 16; sh <<= 1)
                    m0 = fmaxf(m0, __shfl_xor(m0, sh, 64));
                if (col == 0)
                    atomicMax(&bestk[mq2 * 32 + mi * 16 + q * 4 + r], keyenc(m0));
            }
        __syncthreads();   // all waves' chunk maxes visible

        float thr[8];
#pragma unroll
        for (int mi = 0; mi < 2; mi++)
#pragma unroll
            for (int r = 0; r < 4; r++)
                thr[mi * 4 + r] = keydec(bestk[mq2 * 32 + mi * 16 + q * 4 + r]) - D_ADM;

        // admission (later-chunk races only tighten thresholds -> still safe)
#pragma unroll
        for (int mi = 0; mi < 2; mi++)
#pragma unroll
            for (int ni = 0; ni < 4; ni++)
#pragma unroll
                for (int r = 0; r < 4; r++) {
                    const float v = acc[mi][ni][r];
                    if (v >= thr[mi * 4 + r]) {
                        const int tok  = mq2 * 32 + mi * 16 + q * 4 + r;
                        const int code = nb * 128 + nq * 64 + ni * 16 + col;
                        const u32 slot = atomicAdd(&cnt[tok], 1u);
                        if (slot < CAP) {
                            const float vc = fminf(fmaxf((v + 16.0f) * 1024.0f, 0.0f), 65535.0f);
                            slots[tok * CAP + slot] = ((u32)vc << 16) | (u32)code;
                        }
                    }
                }
    }

    __syncthreads();
    // ---- compaction vs final best ----
    if (t < 128) {
        const size_t tokg = tok_base + t;
        const u32 c = cnt[t];
        if (c > CAP) {
            cnt_g[tokg] = 0xFFFFFFFFu;           // overflow sentinel -> full scan
        } else {
            const float thrf = keydec(bestk[t]) - D_FIL;
            u32 m = 0;
            for (u32 i = 0; i < c; i++) {
                const u32 s = slots[t * CAP + i];
                const float approx = (float)(s >> 16) * (1.0f / 1024.0f) - 16.0f;
                if (approx >= thrf) cand_g[tokg * 16 + (m++)] = (u16)(s & 0xFFFFu);
            }
            cnt_g[tokg] = m;                      // >= 1 guaranteed
        }
    }
}

// --------------------------------------------------------------------------
// K3 pick: 16 lanes per token. sc==1 -> winner known (no rescore). Else fp32
// rescore survivors (lowest idx on fp32 ties). Fused loss + mask scatter.
// Barrier-free: per-wave shuffle sum + one double atomic per wave.
// --------------------------------------------------------------------------
__global__ __launch_bounds__(256)
void k_pick(const float* __restrict__ z, const float* __restrict__ W,
            const float* __restrict__ inv_norm, const u16* __restrict__ cand_g,
            const u32* __restrict__ cnt_g, int* __restrict__ mask,
            double* __restrict__ lacc) {
    const int t    = threadIdx.x;
    const int lane = t & 63;
    const int w    = t >> 6;
    const int gl   = t & 15;
    const int grp  = t >> 4;                      // 0..15
    const size_t tok = (size_t)blockIdx.x * 16 + grp;

    float4 zv[4];
#pragma unroll
    for (int j = 0; j < 4; j++)
        zv[j] = reinterpret_cast<const float4*>(z + tok * E_DIM)[j * 16 + gl];

    const u32 sc = cnt_g[tok];
    int bi;
    if (sc == 1u) {
        bi = cand_g[tok * 16];
    } else {
        float bv = -3.4e38f;
        bi = 0x7FFFFFFF;
        const bool full = (sc == 0xFFFFFFFFu);
        const int n_it = full ? N_E : (int)sc;
#pragma unroll 1
        for (int i = 0; i < n_it; i++) {
            const int c = full ? i : (int)cand_g[tok * 16 + i];
            float p = 0.f;
#pragma unroll
            for (int j = 0; j < 4; j++) {
                const float4 wv = reinterpret_cast<const float4*>(W + (size_t)c * E_DIM)[j * 16 + gl];
                p += zv[j].x * wv.x + zv[j].y * wv.y + zv[j].z * wv.z + zv[j].w * wv.w;
            }
#pragma unroll
            for (int sh = 1; sh < 16; sh <<= 1) p += __shfl_xor(p, sh, 64);
            const float s = p * inv_norm[c];
            if (s > bv || (s == bv && c < bi)) { bv = s; bi = c; }
        }
    }

    float lsum = 0.f;
#pragma unroll
    for (int j = 0; j < 4; j++) {
        const float4 wv = reinterpret_cast<const float4*>(W + (size_t)bi * E_DIM)[j * 16 + gl];
        const float dx = zv[j].x - wv.x, dy = zv[j].y - wv.y;
        const float dz2 = zv[j].z - wv.z, dw = zv[j].w - wv.w;
        lsum += dx * dx + dy * dy + dz2 * dz2 + dw * dw;
    }
    if (gl == 0) mask[bi] = 1;                    // benign race

#pragma unroll
    for (int sh = 1; sh < 64; sh <<= 1) lsum += __shfl_xor(lsum, sh, 64);
    if (lane == 0) atomicAdd(&lacc[(blockIdx.x * 4 + w) & 255], (double)lsum);
}

// --------------------------------------------------------------------------
// K4 emit (fused rank): each block redundantly reduces the mask to get
// prefix(e) and total; writes emb row + label. Block 0 finalizes loss.
// --------------------------------------------------------------------------
__global__ __launch_bounds__(256)
void k_emit(const float* __restrict__ W, const int* __restrict__ mask,
            const double* __restrict__ lacc, float* __restrict__ out) {
    __shared__ int   redp[256], redt[256];
    __shared__ double dred[256];
    const int e = blockIdx.x;              // 1024
    const int t = threadIdx.x;             // 256
    const int4 mv = reinterpret_cast<const int4*>(mask)[t];
    const int b = t * 4;
    redt[t] = mv.x + mv.y + mv.z + mv.w;
    redp[t] = (b + 0 < e ? mv.x : 0) + (b + 1 < e ? mv.y : 0) +
              (b + 2 < e ? mv.z : 0) + (b + 3 < e ? mv.w : 0);
    if (e == 0) dred[t] = lacc[t];
    __syncthreads();
#pragma unroll
    for (int s2 = 128; s2 > 0; s2 >>= 1) {
        if (t < s2) {
            redp[t] += redp[t + s2];
            redt[t] += redt[t + s2];
            if (e == 0) dred[t] += dred[t + s2];
        }
        __syncthreads();
    }
    const int prefix = redp[0], total = redt[0];
    const int m = mask[e];
    const int r = m ? prefix : (total + e - prefix);
    out[(size_t)r * E_DIM + t] = W[(size_t)e * E_DIM + t];
    if (t == 0) out[(size_t)N_E * E_DIM + r] = m ? 1.0f : 0.0f;
    if (e == 0 && t == 0) {
        const double mse = dred[0] / (double)((size_t)N_TOK * E_DIM);
        out[(size_t)N_E * E_DIM + N_E] = (float)((1.0 + (double)BETA) * mse);
    }
}

// --------------------------------------------------------------------------
extern "C" void kernel_launch(void* const* d_in, const int* in_sizes, int n_in,
                              void* d_out, int out_size, void* d_ws, size_t ws_size,
                              hipStream_t stream) {
    const float* z = (const float*)d_in[0];
    const float* W = (const float*)d_in[1];
    float* out = (float*)d_out;
    char* ws = (char*)d_ws;

    float*  inv_norm = (float*)(ws + WS_INVNORM);
    int*    mask     = (int*)(ws + WS_MASK);
    double* lacc     = (double*)(ws + WS_LACC);
    u16*    Wsw      = (u16*)(ws + WS_WSW);
    u32*    cnt      = (u32*)(ws + WS_CNT);
    u16*    cand     = (u16*)(ws + WS_CAND);

    k_prep <<<N_E, 64, 0, stream>>>(W, Wsw, inv_norm, mask, lacc);
    k_score<<<N_TOK / 128, 512, 0, stream>>>(z, Wsw, cand, cnt);
    k_pick <<<N_TOK / 16, 256, 0, stream>>>(z, W, inv_norm, cand, cnt, mask, lacc);
    k_emit <<<N_E, 256, 0, stream>>>(W, mask, lacc, out);
}